// Round 7
// baseline (133.903 us; speedup 1.0000x reference)
//
#include <hip/hip_runtime.h>

// SOM update, M=N=512, DIM=256 (=64 float4), NITER=100, ALPHA=0.3, SIGMA=256.
// locations[row] = (row >> 9, row & 511)
// Two dispatches, no atomics:
//   1) BMU: per-block best packed key -> ws[blockIdx]   (2048 x u64)
//   2) update: w-loads issued BEFORE the redundant key-reduce (latency hide),
//      then software-pipelined stream w -> out.

#define MN      (512 * 512)
#define NCOL    512
#define NBLOCKS 2048

typedef float vfloat4 __attribute__((ext_vector_type(4)));  // native vec for nontemporal builtin

// ---------------- kernel 1: BMU argmin ----------------
// 16 lanes per row, 4 rows per wave iteration. Lane (16*sub + c) accumulates
// chunks k=0..3 of row (4*G+sub): elements [k*64 + c*4, +4).
// Packed key (distbits<<32 | row) -> min == first-occurrence argmin.
__global__ __launch_bounds__(256) void som_bmu_kernel(
        const float* __restrict__ x,
        const float* __restrict__ w,
        unsigned long long* __restrict__ ws) {
    const int lane        = threadIdx.x & 63;
    const int sub         = lane >> 4;     // row within 4-row group
    const int c           = lane & 15;     // 16B chunk within row
    const int waveInBlock = threadIdx.x >> 6;
    const int wavesPerBlk = blockDim.x >> 6;            // 4
    const int waveId      = blockIdx.x * wavesPerBlk + waveInBlock;
    const int nWaves      = gridDim.x * wavesPerBlk;    // 8192

    // x fragments this lane needs: x[k*64 + c*4 .. +4)
    float4 xv[4];
    #pragma unroll
    for (int k = 0; k < 4; ++k)
        xv[k] = reinterpret_cast<const float4*>(x)[k * 16 + c];

    unsigned long long bestKey = 0xFFFFFFFFFFFFFFFFull;

    for (int G = waveId; G < MN / 4; G += nWaves) {     // 8 iterations
        const int row = G * 4 + sub;
        const float4* wr = reinterpret_cast<const float4*>(w + (size_t)row * 256);
        float s = 0.0f;
        #pragma unroll
        for (int k = 0; k < 4; ++k) {
            const float4 wv = wr[k * 16 + c];
            const float d0 = xv[k].x - wv.x;
            const float d1 = xv[k].y - wv.y;
            const float d2 = xv[k].z - wv.z;
            const float d3 = xv[k].w - wv.w;
            s += d0 * d0 + d1 * d1 + d2 * d2 + d3 * d3;
        }
        // butterfly within 16-lane group: all lanes get the row's sum,
        // bitwise-identical across lanes (symmetric pair adds)
        #pragma unroll
        for (int m = 1; m < 16; m <<= 1) s += __shfl_xor(s, m);

        const unsigned long long key =
            ((unsigned long long)__float_as_uint(s) << 32) | (unsigned int)row;
        if (key < bestKey) bestKey = key;
    }

    // reduce the 4 row-groups across the wave
    #pragma unroll
    for (int m = 16; m < 64; m <<= 1) {
        const unsigned long long o = __shfl_xor(bestKey, m);
        if (o < bestKey) bestKey = o;
    }

    __shared__ unsigned long long skeys[4];
    if (lane == 0) skeys[waveInBlock] = bestKey;
    __syncthreads();
    if (threadIdx.x == 0) {
        unsigned long long k = skeys[0];
        #pragma unroll
        for (int i = 1; i < 4; ++i)
            if (skeys[i] < k) k = skeys[i];
        ws[blockIdx.x] = k;          // unconditional: no init, no atomics
    }
}

// ---------------- kernel 2: fused neighborhood update ----------------
// First 4-row w batch + x issued BEFORE the key-reduce so HBM loads hide the
// cross-XCD key-gather latency. Then software-pipelined: prefetch batch k+1
// while computing/storing batch k. Nontemporal stores (out never re-read).
__global__ __launch_bounds__(256) void som_update_kernel(
        const float* __restrict__ x,
        const float* __restrict__ w,
        const int* __restrict__ it_p,
        const unsigned long long* __restrict__ ws,
        float* __restrict__ out) {
    const int lane   = threadIdx.x & 63;
    const int waveId = (int)((blockIdx.x * blockDim.x + threadIdx.x) >> 6);
    const int nWaves = (int)((gridDim.x * blockDim.x) >> 6);  // 8192

    // ---- issue independent loads first: x + w batch 0 ----
    const float4 xv = reinterpret_cast<const float4*>(x)[lane];
    float4 wv[4];
    #pragma unroll
    for (int k2 = 0; k2 < 4; ++k2)
        wv[k2] = reinterpret_cast<const float4*>(
                     w + (size_t)(waveId + k2 * nWaves) * 256)[lane];

    // ---- reduce 2048 keys -> global argmin (every block, redundantly) ----
    unsigned long long k = 0xFFFFFFFFFFFFFFFFull;
    #pragma unroll
    for (int i = 0; i < NBLOCKS / 256; ++i) {           // 8 slots/thread
        const unsigned long long v = ws[threadIdx.x + i * 256];
        if (v < k) k = v;
    }
    #pragma unroll
    for (int m = 1; m < 64; m <<= 1) {
        const unsigned long long o = __shfl_xor(k, m);
        if (o < k) k = o;
    }
    __shared__ unsigned long long skeys[4];
    if ((threadIdx.x & 63) == 0) skeys[threadIdx.x >> 6] = k;
    __syncthreads();
    unsigned long long key = skeys[0];
    #pragma unroll
    for (int i = 1; i < 4; ++i)
        if (skeys[i] < key) key = skeys[i];

    const int bmu = (int)(key & 0xFFFFFFFFull);
    const int bi  = bmu >> 9;
    const int bj  = bmu & (NCOL - 1);

    const float lr       = 1.0f - (float)(*it_p) * 0.01f;   // 1 - it/NITER
    const float alpha_op = 0.3f * lr;
    const float sigma_op = 256.0f * lr;
    const float inv_s2   = 1.0f / (sigma_op * sigma_op);

    // ---- software-pipelined stream: 8 batches x 4 rows ----
    const int NBATCH = MN / (4 * nWaves);               // 8
    int base = waveId;
    for (int b = 0; b < NBATCH; ++b) {
        const int nextBase = base + 4 * nWaves;
        float4 nv[4];
        if (b + 1 < NBATCH) {
            #pragma unroll
            for (int k2 = 0; k2 < 4; ++k2)
                nv[k2] = reinterpret_cast<const float4*>(
                             w + (size_t)(nextBase + k2 * nWaves) * 256)[lane];
        }
        #pragma unroll
        for (int k2 = 0; k2 < 4; ++k2) {
            const int row = base + k2 * nWaves;
            const int i = row >> 9;
            const int j = row & (NCOL - 1);
            const float di = (float)(i - bi);
            const float dj = (float)(j - bj);
            const float f  = alpha_op * __expf(-(di * di + dj * dj) * inv_s2);
            vfloat4 o;
            o.x = wv[k2].x + f * (xv.x - wv[k2].x);
            o.y = wv[k2].y + f * (xv.y - wv[k2].y);
            o.z = wv[k2].z + f * (xv.z - wv[k2].z);
            o.w = wv[k2].w + f * (xv.w - wv[k2].w);
            __builtin_nontemporal_store(
                o, reinterpret_cast<vfloat4*>(out + (size_t)row * 256) + lane);
        }
        #pragma unroll
        for (int k2 = 0; k2 < 4; ++k2) wv[k2] = nv[k2];
        base = nextBase;
    }
}

extern "C" void kernel_launch(void* const* d_in, const int* in_sizes, int n_in,
                              void* d_out, int out_size, void* d_ws, size_t ws_size,
                              hipStream_t stream) {
    const float* x  = (const float*)d_in[0];
    const float* w  = (const float*)d_in[1];
    const int*   it = (const int*)d_in[2];
    float* out = (float*)d_out;
    unsigned long long* ws = (unsigned long long*)d_ws;

    // BMU: 2048 blocks x 4 waves = 8192 waves; per-block key -> ws[bid]
    som_bmu_kernel<<<NBLOCKS, 256, 0, stream>>>(x, w, ws);

    // Update: prefetch-before-reduce, software-pipelined stream w -> out
    som_update_kernel<<<NBLOCKS, 256, 0, stream>>>(x, w, it, ws, out);
}

// Round 8
// 129.368 us; speedup vs baseline: 1.0351x; 1.0351x over previous
//
#include <hip/hip_runtime.h>

// SOM update, M=N=512, DIM=256 (=64 float4), NITER=100, ALPHA=0.3, SIGMA=256.
// locations[row] = (row >> 9, row & 511)
// Two dispatches, no atomics:
//   1) BMU: per-block best packed key -> ws[blockIdx]   (2048 x u64)
//   2) update: per-block redundant reduce of the 2048 keys (L2), then stream.
// R7 post-mortem: explicit software-pipelining/prefetch REGRESSED (134 vs 130)
// -- compiler's schedule + 32 waves/CU already covers HBM latency. Keep simple.

#define MN      (512 * 512)
#define NCOL    512
#define NBLOCKS 2048

typedef float vfloat4 __attribute__((ext_vector_type(4)));  // native vec for nontemporal builtin

// ---------------- kernel 1: BMU argmin ----------------
// 16 lanes per row, 4 rows per wave iteration. Lane (16*sub + c) accumulates
// chunks k=0..3 of row (4*G+sub): elements [k*64 + c*4, +4).
// Packed key (distbits<<32 | row) -> min == first-occurrence argmin.
__global__ __launch_bounds__(256) void som_bmu_kernel(
        const float* __restrict__ x,
        const float* __restrict__ w,
        unsigned long long* __restrict__ ws) {
    const int lane        = threadIdx.x & 63;
    const int sub         = lane >> 4;     // row within 4-row group
    const int c           = lane & 15;     // 16B chunk within row
    const int waveInBlock = threadIdx.x >> 6;
    const int wavesPerBlk = blockDim.x >> 6;            // 4
    const int waveId      = blockIdx.x * wavesPerBlk + waveInBlock;
    const int nWaves      = gridDim.x * wavesPerBlk;    // 8192

    // x fragments this lane needs: x[k*64 + c*4 .. +4)
    float4 xv[4];
    #pragma unroll
    for (int k = 0; k < 4; ++k)
        xv[k] = reinterpret_cast<const float4*>(x)[k * 16 + c];

    unsigned long long bestKey = 0xFFFFFFFFFFFFFFFFull;

    for (int G = waveId; G < MN / 4; G += nWaves) {     // 8 iterations
        const int row = G * 4 + sub;
        const float4* wr = reinterpret_cast<const float4*>(w + (size_t)row * 256);
        float s = 0.0f;
        #pragma unroll
        for (int k = 0; k < 4; ++k) {
            const float4 wv = wr[k * 16 + c];
            const float d0 = xv[k].x - wv.x;
            const float d1 = xv[k].y - wv.y;
            const float d2 = xv[k].z - wv.z;
            const float d3 = xv[k].w - wv.w;
            s += d0 * d0 + d1 * d1 + d2 * d2 + d3 * d3;
        }
        // butterfly within 16-lane group: all lanes get the row's sum,
        // bitwise-identical across lanes (symmetric pair adds)
        #pragma unroll
        for (int m = 1; m < 16; m <<= 1) s += __shfl_xor(s, m);

        const unsigned long long key =
            ((unsigned long long)__float_as_uint(s) << 32) | (unsigned int)row;
        if (key < bestKey) bestKey = key;
    }

    // reduce the 4 row-groups across the wave
    #pragma unroll
    for (int m = 16; m < 64; m <<= 1) {
        const unsigned long long o = __shfl_xor(bestKey, m);
        if (o < bestKey) bestKey = o;
    }

    __shared__ unsigned long long skeys[4];
    if (lane == 0) skeys[waveInBlock] = bestKey;
    __syncthreads();
    if (threadIdx.x == 0) {
        unsigned long long k = skeys[0];
        #pragma unroll
        for (int i = 1; i < 4; ++i)
            if (skeys[i] < k) k = skeys[i];
        ws[blockIdx.x] = k;          // unconditional: no init, no atomics
    }
}

// ---------------- kernel 2: fused neighborhood update ----------------
// Per-block redundant argmin reduce over the 2048 keys (16KB, L2-served),
// then one wave per row, 4 rows in flight, forward slab order.
// Nontemporal stores for `out` (never re-read).
__global__ __launch_bounds__(256) void som_update_kernel(
        const float* __restrict__ x,
        const float* __restrict__ w,
        const int* __restrict__ it_p,
        const unsigned long long* __restrict__ ws,
        float* __restrict__ out) {
    // ---- reduce 2048 keys -> global argmin (every block, redundantly) ----
    unsigned long long k = 0xFFFFFFFFFFFFFFFFull;
    #pragma unroll
    for (int i = 0; i < NBLOCKS / 256; ++i) {           // 8 slots/thread
        const unsigned long long v = ws[threadIdx.x + i * 256];
        if (v < k) k = v;
    }
    #pragma unroll
    for (int m = 1; m < 64; m <<= 1) {
        const unsigned long long o = __shfl_xor(k, m);
        if (o < k) k = o;
    }
    __shared__ unsigned long long skeys[4];
    if ((threadIdx.x & 63) == 0) skeys[threadIdx.x >> 6] = k;
    __syncthreads();
    unsigned long long key = skeys[0];
    #pragma unroll
    for (int i = 1; i < 4; ++i)
        if (skeys[i] < key) key = skeys[i];

    const int bmu = (int)(key & 0xFFFFFFFFull);
    const int bi  = bmu >> 9;
    const int bj  = bmu & (NCOL - 1);

    const float lr       = 1.0f - (float)(*it_p) * 0.01f;   // 1 - it/NITER
    const float alpha_op = 0.3f * lr;
    const float sigma_op = 256.0f * lr;
    const float inv_s2   = 1.0f / (sigma_op * sigma_op);

    const int lane   = threadIdx.x & 63;
    const int waveId = (int)((blockIdx.x * blockDim.x + threadIdx.x) >> 6);
    const int nWaves = (int)((gridDim.x * blockDim.x) >> 6);  // 8192

    const float4 xv = reinterpret_cast<const float4*>(x)[lane];

    // 32 rows per wave: 8 outer iterations x 4 rows in flight
    for (int base = waveId; base < MN; base += 4 * nWaves) {
        float4 wv[4];
        int    rows[4];
        #pragma unroll
        for (int k2 = 0; k2 < 4; ++k2) {
            rows[k2] = base + k2 * nWaves;
            wv[k2] = reinterpret_cast<const float4*>(
                         w + (size_t)rows[k2] * 256)[lane];
        }
        #pragma unroll
        for (int k2 = 0; k2 < 4; ++k2) {
            const int row = rows[k2];
            const int i = row >> 9;
            const int j = row & (NCOL - 1);
            const float di = (float)(i - bi);
            const float dj = (float)(j - bj);
            const float f  = alpha_op * __expf(-(di * di + dj * dj) * inv_s2);
            vfloat4 o;
            o.x = wv[k2].x + f * (xv.x - wv[k2].x);
            o.y = wv[k2].y + f * (xv.y - wv[k2].y);
            o.z = wv[k2].z + f * (xv.z - wv[k2].z);
            o.w = wv[k2].w + f * (xv.w - wv[k2].w);
            __builtin_nontemporal_store(
                o, reinterpret_cast<vfloat4*>(out + (size_t)row * 256) + lane);
        }
    }
}

extern "C" void kernel_launch(void* const* d_in, const int* in_sizes, int n_in,
                              void* d_out, int out_size, void* d_ws, size_t ws_size,
                              hipStream_t stream) {
    const float* x  = (const float*)d_in[0];
    const float* w  = (const float*)d_in[1];
    const int*   it = (const int*)d_in[2];
    float* out = (float*)d_out;
    unsigned long long* ws = (unsigned long long*)d_ws;

    // BMU: 2048 blocks x 4 waves = 8192 waves; per-block key -> ws[bid]
    som_bmu_kernel<<<NBLOCKS, 256, 0, stream>>>(x, w, ws);

    // Update: redundant key-reduce per block, then stream w -> out
    som_update_kernel<<<NBLOCKS, 256, 0, stream>>>(x, w, it, ws, out);
}